// Round 6
// baseline (439.267 us; speedup 1.0000x reference)
//
#include <hip/hip_runtime.h>
#include <cstdint>

#define KDIM 4096
#define NNODE 4096
#define TSTEPS 128            // K-steps of 32 over KDIM

typedef __bf16 bf16x8 __attribute__((ext_vector_type(8)));
typedef float floatx4 __attribute__((ext_vector_type(4)));

__device__ __forceinline__ uint16_t f2b(float f) {
  union { float f; uint32_t u; } v; v.f = f;
  uint32_t u = v.u;
  return (uint16_t)((u + 0x7FFFu + ((u >> 16) & 1u)) >> 16);  // RNE
}
__device__ __forceinline__ float b2f(uint16_t h) {
  union { uint32_t u; float f; } v; v.u = ((uint32_t)h) << 16; return v.f;
}
__device__ __forceinline__ uint32_t pack2(float a, float b) {
  return (uint32_t)f2b(a) | ((uint32_t)f2b(b) << 16);
}

// Fragment layout (both GEMM operands): frag[f16][t][lane][8] where
// elem = M[f16*16 + mr][t*32 + q*8 + j], lane = q*16 + mr.
// A wave's fragment load = base + lane*16B -> one fully-coalesced 1KB dwordx4.

// ---------- supports: fp32 row-major -> bf16 fragment layout ----------
__global__ __launch_bounds__(256) void cvt_supports(
    const float* __restrict__ s0, const float* __restrict__ s1,
    uint16_t* __restrict__ d0, uint16_t* __restrict__ d1) {
  const float* src = blockIdx.z ? s1 : s0;
  uint16_t* dst = blockIdx.z ? d1 : d0;
  const int c16 = blockIdx.x, kb = blockIdx.y;      // 256 x 32
  const int col_in = threadIdx.x >> 4, k8 = threadIdx.x & 15;
  const int col = c16 * 16 + col_in;
  const int k = kb * 128 + k8 * 8;
  const float* p = src + (size_t)col * KDIM + k;
  float4 v0 = *(const float4*)p;
  float4 v1 = *(const float4*)(p + 4);
  uint4 o;
  o.x = pack2(v0.x, v0.y); o.y = pack2(v0.z, v0.w);
  o.z = pack2(v1.x, v1.y); o.w = pack2(v1.z, v1.w);
  size_t off = ((size_t)(c16 * 128 + kb * 4 + (k8 >> 2))) * 512 +
               (size_t)((k8 & 3) * 16 + col_in) * 8;
  *(uint4*)(dst + off) = o;
}

// ---------- X1 (gemm1 A): rows (b,[feats(2);prev(16)]) -> fragment layout ----------
__global__ __launch_bounds__(256) void pack_x1(
    const float* __restrict__ inp, const float* __restrict__ st,
    uint16_t* __restrict__ X1) {
  const int r16 = blockIdx.x, kb = blockIdx.y;      // 72 x 32
  const int row_in = threadIdx.x >> 4, k8 = threadIdx.x & 15;
  const int row = r16 * 16 + row_in;
  const int k = kb * 128 + k8 * 8;
  int b = row / 18, c = row - b * 18;
  const float* p = (c < 2) ? (inp + (size_t)b * 8192 + (size_t)c * 4096 + k)
                           : (st + (size_t)b * 65536 + (size_t)(c - 2) * 4096 + k);
  float4 v0 = *(const float4*)p;
  float4 v1 = *(const float4*)(p + 4);
  uint4 o;
  o.x = pack2(v0.x, v0.y); o.y = pack2(v0.z, v0.w);
  o.z = pack2(v1.x, v1.y); o.w = pack2(v1.z, v1.w);
  size_t off = ((size_t)(r16 * 128 + kb * 4 + (k8 >> 2))) * 512 +
               (size_t)((k8 & 3) * 16 + row_in) * 8;
  *(uint4*)(X1 + off) = o;
}

// direct global->LDS, 16B per lane; LDS dest is wave-uniform base + lane*16
__device__ __forceinline__ void gl_lds16(const uint16_t* g, uint16_t* l) {
  __builtin_amdgcn_global_load_lds(
      (const __attribute__((address_space(1))) uint32_t*)g,
      (__attribute__((address_space(3))) uint32_t*)l, 16, 0, 0);
}

// ---------- fat-tile fragment GEMM (R6) ----------
// R5 post-mortem: structure was LDS-READ-throughput-bound (ds_read_b128 ~85
// B/cy/CU; 88KB reads vs 698 MFMA cyc per chunk -> MfmaUtil capped ~50%).
// R6 fattens the wave tile to cut LDS bytes/FLOP ~1.6x:
//   MODE1: block 288x256 (1152=4x288), waves 2x4, wave 144x64 (AR=9,BR=4).
//          Per K=32 chunk: 288 MFMA = 1396 cyc vs 104KB reads = 1224 -> MFMA-bound.
//   MODE3: block 256x256, waves 2x4, wave 128x64 (AR=8,BR=4).
//          256 MFMA = 1241 cyc vs 96KB = 1129 -> MFMA-bound.
// KSPLIT=2 restores exact 256-block grids (16x4x4), 1 block/CU, 512 thr.
// 4 LDS buffers of (MFR+16) KB (136/128 KB). Depth-3 counted-vmcnt staging
// (stage chunk c+3; wait leaves 2 chunks in flight). Non-uniform staging:
// 34 slots (MODE1) -> waves 0,1 stage 5 frags, waves 2-7 stage 4; per-wave
// vmcnt literals. VGPR budget (acc 144) forces ASYMMETRIC reg pipeline:
// B(c+1) prefetched into alternate reg set; A(c) read same-iter, then
// lgkmcnt(4) drains A while B-next flies. A-exposure (~200cy) is covered by
// the SIMD-mate wave's MFMA. Buffer safety as R5: STAGE target's last reads
// drained by the previous iter's waitLG, ~1 full iter + barrier of slack.
template <int MODE>
__global__ __launch_bounds__(512, 2) void gemm_frag(
    const uint16_t* __restrict__ Af, const uint16_t* __restrict__ S0f,
    const uint16_t* __restrict__ S1f, uint16_t* __restrict__ D) {
  constexpr int CPB   = (MODE == 1) ? 18 : 16;
  constexpr int OUTC  = (MODE == 1) ? 36 : 32;
  constexpr int MFR   = (MODE == 1) ? 18 : 16;  // A frag-rows per block tile
  constexpr int AR    = MFR / 2;                // 9 / 8 (wave grid 2x4)
  constexpr int BR    = 4;                      // 16 / 4
  constexpr int NREAL = MFR + 16;               // 34 / 32 frag slots
  constexpr int EXTRA = NREAL - 32;             // 2 / 0 (waves with 5 loads)
  constexpr int NCH   = 64;                     // K chunks of 32 per ks half
  constexpr size_t PSTRIDE = (size_t)64 * OUTC * NNODE;

  __shared__ uint16_t sAB[4][NREAL][512];       // 136 KiB / 128 KiB

  const int lane = threadIdx.x & 63, wave = threadIdx.x >> 6;
  const int wr = wave >> 2, wc = wave & 3;
  const int s = blockIdx.z & 1, ks = blockIdx.z >> 1;
  const uint16_t* __restrict__ Bf = s ? S1f : S0f;
  const int yF = blockIdx.y * MFR;   // A frag-row base
  const int xF = blockIdx.x * 16;    // B frag-col base (256 cols)
  const int tBeg = ks * NCH;

  const int lpw = (EXTRA && wave < EXTRA) ? 5 : 4;
  const int slotbase = 4 * wave + (wave < EXTRA ? wave : EXTRA);

  const uint16_t* Gp[5];
#pragma unroll
  for (int i = 0; i < 5; ++i) {
    int sid = slotbase + i;
    if (i < lpw && sid < NREAL) {
      const uint16_t* base = (sid < MFR) ? Af : Bf;
      int fr = (sid < MFR) ? (yF + sid) : (xF + (sid - MFR));
      Gp[i] = base + ((size_t)fr * TSTEPS + tBeg) * 512 + (size_t)lane * 8;
    } else Gp[i] = Af;
  }

  floatx4 acc[AR][BR];
#pragma unroll
  for (int i = 0; i < AR; ++i)
#pragma unroll
    for (int j = 0; j < BR; ++j) acc[i][j] = (floatx4){0.f, 0.f, 0.f, 0.f};

  auto STAGE = [&](int bi, int c) {
    uint16_t* l = &sAB[bi][slotbase][0];
    const size_t off = (size_t)c * 512;
#pragma unroll
    for (int i = 0; i < 5; ++i)
      if (i < lpw) gl_lds16(Gp[i] + off, l + (size_t)i * 512);
  };

  auto LDREG_A = [&](int bi, bf16x8* a) {
    const uint16_t* base = &sAB[bi][0][lane * 8];
#pragma unroll
    for (int rt = 0; rt < AR; ++rt)
      a[rt] = *(const bf16x8*)(base + (size_t)(wr * AR + rt) * 512);
  };
  auto LDREG_B = [&](int bi, bf16x8* b) {
    const uint16_t* base = &sAB[bi][0][lane * 8];
#pragma unroll
    for (int ct = 0; ct < BR; ++ct)
      b[ct] = *(const bf16x8*)(base + (size_t)(MFR + wc * BR + ct) * 512);
  };

  auto MFMAALL = [&](bf16x8* a, bf16x8* b) {
    __builtin_amdgcn_s_setprio(1);
#pragma unroll
    for (int rt = 0; rt < AR; ++rt)
#pragma unroll
      for (int ct = 0; ct < BR; ++ct)
        acc[rt][ct] = __builtin_amdgcn_mfma_f32_16x16x32_bf16(
            a[rt], b[ct], acc[rt][ct], 0, 0, 0);
    __builtin_amdgcn_s_setprio(0);
  };

  auto waitVM = [&] {  // chunk c+1 landed; 2 chunks (2*lpw loads) in flight
    if constexpr (EXTRA > 0) {
      if (wave < EXTRA) asm volatile("s_waitcnt vmcnt(10)" ::: "memory");
      else              asm volatile("s_waitcnt vmcnt(8)" ::: "memory");
    } else {
      asm volatile("s_waitcnt vmcnt(8)" ::: "memory");
    }
  };

  // prologue: chunks 0,1,2 staged; B(0) -> reg set A
  STAGE(0, 0);
  STAGE(1, 1);
  STAGE(2, 2);
  waitVM();
  __builtin_amdgcn_sched_barrier(0);
  __builtin_amdgcn_s_barrier();
  __builtin_amdgcn_sched_barrier(0);
  bf16x8 aR[AR], bA[BR], bB[BR];
  LDREG_B(0, bA);

  // iter c: STAGE c+3; barrier; read A(c) + B(c+1)->alt; lgkmcnt(4) (A done,
  // B-next flying); MFMA(A(c), B(c) from prev iter's prefetch).
#define GITER(J, STB, ABUF, BBUF, CURB, NXTB)                               \
  {                                                                         \
    int cl = c0 + 3 + (J);                                                  \
    if (cl > NCH - 1) cl = NCH - 1; /* clamped redundant tail stage */      \
    STAGE((STB), cl);                                                       \
    waitVM();                                                               \
    __builtin_amdgcn_sched_barrier(0);                                      \
    __builtin_amdgcn_s_barrier();                                           \
    __builtin_amdgcn_sched_barrier(0);                                      \
    LDREG_A((ABUF), aR);                                                    \
    LDREG_B((BBUF), NXTB);                                                  \
    asm volatile("s_waitcnt lgkmcnt(4)" ::: "memory");                      \
    __builtin_amdgcn_sched_barrier(0);                                      \
    MFMAALL(aR, CURB);                                                      \
    __builtin_amdgcn_sched_barrier(0);                                      \
  }

  for (int m = 0; m < NCH / 4; ++m) {
    const int c0 = m * 4;
    GITER(0, 3, 0, 1, bA, bB)   // c0  : A buf0, B(c+1) buf1 -> bB, MFMA w/ bA
    GITER(1, 0, 1, 2, bB, bA)   // c0+1
    GITER(2, 1, 2, 3, bA, bB)   // c0+2
    GITER(3, 2, 3, 0, bB, bA)   // c0+3 (tail: B-read junk, unused)
  }
#undef GITER

  uint16_t* Dp = D + (size_t)ks * PSTRIDE;
  // epilogue: C/D layout col=lane&15, row=(lane>>4)*4+reg; D row-major bf16
#pragma unroll
  for (int rt = 0; rt < AR; ++rt) {
#pragma unroll
    for (int r = 0; r < 4; ++r) {
      int rowg = (yF + wr * AR + rt) * 16 + (lane >> 4) * 4 + r;
      int b = rowg / CPB, c = rowg - b * CPB;
      int jj;
      if (MODE == 1) jj = (c < 2) ? (2 * s + c) : (4 + 16 * s + (c - 2));
      else jj = 16 * s + c;
      uint16_t* drow = Dp + (size_t)(b * OUTC + jj) * NNODE;
#pragma unroll
      for (int ct = 0; ct < BR; ++ct) {
        int colg = (xF + wc * BR + ct) * 16 + (lane & 15);
        drow[colg] = f2b(acc[rt][ct][r]);
      }
    }
  }
}

// ---------- stage2: r,u gates; X2 = r*prev -> fragment layout via LDS transpose ----------
__global__ __launch_bounds__(256) void stage2(
    const uint16_t* __restrict__ P1, const float* __restrict__ state,
    const float* __restrict__ rk, const float* __restrict__ uk,
    uint16_t* __restrict__ X2f, float* __restrict__ U) {
  constexpr size_t PS = (size_t)64 * 36 * NNODE;
  __shared__ float s_rk[576], s_uk[576];
  __shared__ uint16_t s_x2[16 * 264];  // [k][i], padded stride (264) vs 256
  for (int i = threadIdx.x; i < 576; i += 256) { s_rk[i] = rk[i]; s_uk[i] = uk[i]; }
  __syncthreads();
  const int b = blockIdx.x >> 4, nb = blockIdx.x & 15;
  const int i = threadIdx.x;
  const int n = nb * 256 + i;
  float hs[36];
  const uint16_t* p = P1 + (size_t)b * 36 * NNODE + n;
#pragma unroll
  for (int j = 0; j < 36; ++j)
    hs[j] = b2f(p[(size_t)j * NNODE]) + b2f(p[PS + (size_t)j * NNODE]);
  float ar[16], au[16];
#pragma unroll
  for (int k = 0; k < 16; ++k) { ar[k] = 0.f; au[k] = 0.f; }
#pragma unroll
  for (int j = 0; j < 36; ++j) {
    float h = hs[j];
#pragma unroll
    for (int k = 0; k < 16; ++k) {
      ar[k] += h * s_rk[j * 16 + k];
      au[k] += h * s_uk[j * 16 + k];
    }
  }
  const float* sp = state + (size_t)b * 65536 + n;
#pragma unroll
  for (int k = 0; k < 16; ++k) {
    float r = 1.f / (1.f + __expf(-ar[k]));
    float uu = 1.f / (1.f + __expf(-au[k]));
    float prev = sp[(size_t)k * NNODE];
    s_x2[k * 264 + i] = f2b(r * prev);
    U[(size_t)(b * 16 + k) * NNODE + n] = uu;
  }
  __syncthreads();
  // flush 4096 bf16 (16 k x 256 n) to fragment layout: contiguous 8KB region.
  uint16_t* region = X2f + ((size_t)b * 128 + nb * 8) * 512;
#pragma unroll
  for (int rr = 0; rr < 2; ++rr) {
    int fid = rr * 256 + i;
    int kk = fid & 15, qq = (fid >> 4) & 3, tl = fid >> 6;
    uint4 v = *(const uint4*)&s_x2[kk * 264 + tl * 32 + qq * 8];
    *(uint4*)(region + (size_t)fid * 8) = v;
  }
}

// ---------- stage4: c = tanh([h;D3]*ck); z = u*prev + (1-u)*c ----------
// OUTPUT LAYOUT: z is (B, N, U) reshaped -> out[b*65536 + n*16 + k]
__global__ __launch_bounds__(256) void stage4(
    const uint16_t* __restrict__ P1, const uint16_t* __restrict__ P3,
    const float* __restrict__ U, const float* __restrict__ state,
    const float* __restrict__ ck, float* __restrict__ out) {
  constexpr size_t PS1 = (size_t)64 * 36 * NNODE;
  constexpr size_t PS3 = (size_t)64 * 32 * NNODE;
  __shared__ float s_ck[576];
  for (int i = threadIdx.x; i < 576; i += 256) s_ck[i] = ck[i];
  __syncthreads();
  int idx = blockIdx.x * 256 + threadIdx.x;
  int b = idx >> 12, n = idx & 4095;
  float hv[36];
  const uint16_t* p1 = P1 + (size_t)b * 36 * NNODE + n;
#pragma unroll
  for (int j = 0; j < 4; ++j)
    hv[j] = b2f(p1[(size_t)j * NNODE]) + b2f(p1[PS1 + (size_t)j * NNODE]);
  const uint16_t* p3 = P3 + (size_t)b * 32 * NNODE + n;
#pragma unroll
  for (int j = 0; j < 32; ++j)
    hv[4 + j] = b2f(p3[(size_t)j * NNODE]) + b2f(p3[PS3 + (size_t)j * NNODE]);
  float ac[16];
#pragma unroll
  for (int k = 0; k < 16; ++k) ac[k] = 0.f;
#pragma unroll
  for (int j = 0; j < 36; ++j) {
    float h = hv[j];
#pragma unroll
    for (int k = 0; k < 16; ++k) ac[k] += h * s_ck[j * 16 + k];
  }
  const float* sp = state + (size_t)b * 65536 + n;
  const float* up = U + (size_t)b * 16 * NNODE + n;
  float z[16];
#pragma unroll
  for (int k = 0; k < 16; ++k) {
    float e = __expf(2.f * ac[k]);
    float c = 1.f - 2.f / (e + 1.f);  // tanh, saturates at +/-inf
    float uu = up[(size_t)k * NNODE];
    float prev = sp[(size_t)k * NNODE];
    z[k] = uu * prev + (1.f - uu) * c;
  }
  float4* po = (float4*)(out + (size_t)b * 65536 + (size_t)n * 16);
#pragma unroll
  for (int k4 = 0; k4 < 4; ++k4)
    po[k4] = make_float4(z[k4 * 4], z[k4 * 4 + 1], z[k4 * 4 + 2], z[k4 * 4 + 3]);
}

extern "C" void kernel_launch(void* const* d_in, const int* in_sizes, int n_in,
                              void* d_out, int out_size, void* d_ws, size_t ws_size,
                              hipStream_t stream) {
  const float* inputs = (const float*)d_in[0];
  const float* state = (const float*)d_in[1];
  const float* s0 = (const float*)d_in[2];
  const float* s1 = (const float*)d_in[3];
  const float* rk = (const float*)d_in[4];
  const float* uk = (const float*)d_in[5];
  const float* ck = (const float*)d_in[6];
  float* out = (float*)d_out;
  char* ws = (char*)d_ws;

  // workspace layout (bytes); X2f aliases X1f (dead after gemm1)
  uint16_t* S0f = (uint16_t*)(ws);                  // 33,554,432
  uint16_t* S1f = (uint16_t*)(ws + 33554432);       // 33,554,432
  uint16_t* X1f = (uint16_t*)(ws + 67108864);       // 9,437,184   (1152 x 4096 bf16, frag)
  uint16_t* X2f = (uint16_t*)(ws + 67108864);       // 8,388,608   (aliases X1f, frag)
  uint16_t* P1 = (uint16_t*)(ws + 76546048);        // 2 x 18,874,368 (split-K partials)
  float* U = (float*)(ws + 114294784);              // 16,777,216
  uint16_t* P3 = (uint16_t*)(ws + 131072000);       // 2 x 16,777,216 (split-K partials)
  // total 164,626,432 bytes

  cvt_supports<<<dim3(256, 32, 2), 256, 0, stream>>>(s0, s1, S0f, S1f);
  pack_x1<<<dim3(72, 32), 256, 0, stream>>>(inputs, state, X1f);
  gemm_frag<1><<<dim3(16, 4, 4), 512, 0, stream>>>(X1f, S0f, S1f, P1);
  stage2<<<1024, 256, 0, stream>>>(P1, state, rk, uk, X2f, U);
  gemm_frag<3><<<dim3(16, 4, 4), 512, 0, stream>>>(X2f, S0f, S1f, P3);
  stage4<<<1024, 256, 0, stream>>>(P1, P3, U, state, ck, out);
}

// Round 7
// 401.228 us; speedup vs baseline: 1.0948x; 1.0948x over previous
//
#include <hip/hip_runtime.h>
#include <cstdint>

#define KDIM 4096
#define NNODE 4096
#define TQ 256                // k-granules of 16 over KDIM

typedef __bf16 bf16x8 __attribute__((ext_vector_type(8)));
typedef float floatx16 __attribute__((ext_vector_type(16)));

__device__ __forceinline__ uint16_t f2b(float f) {
  union { float f; uint32_t u; } v; v.f = f;
  uint32_t u = v.u;
  return (uint16_t)((u + 0x7FFFu + ((u >> 16) & 1u)) >> 16);  // RNE
}
__device__ __forceinline__ float b2f(uint16_t h) {
  union { uint32_t u; float f; } v; v.u = ((uint32_t)h) << 16; return v.f;
}
__device__ __forceinline__ uint32_t pack2(float a, float b) {
  return (uint32_t)f2b(a) | ((uint32_t)f2b(b) << 16);
}

// 32-row fragment layout (both GEMM operands, for mfma_f32_32x32x16_bf16):
// frag[f][t][lane][8]: elem = M[f*32 + mr][t*16 + q*8 + j], lane = q*32 + mr
// (q in {0,1}). One fragment-granule = 1KB; wave load = base + lane*16B.

// ---------- supports: fp32 row-major -> bf16 32-frag layout ----------
__global__ __launch_bounds__(256) void cvt_supports(
    const float* __restrict__ s0, const float* __restrict__ s1,
    uint16_t* __restrict__ d0, uint16_t* __restrict__ d1) {
  const float* src = blockIdx.z ? s1 : s0;
  uint16_t* dst = blockIdx.z ? d1 : d0;
  const int c16 = blockIdx.x, kb = blockIdx.y;      // 256 x 32
  const int col_in = threadIdx.x >> 4, k8 = threadIdx.x & 15;
  const int col = c16 * 16 + col_in;
  const int k = kb * 128 + k8 * 8;
  const float* p = src + (size_t)col * KDIM + k;
  float4 v0 = *(const float4*)p;
  float4 v1 = *(const float4*)(p + 4);
  uint4 o;
  o.x = pack2(v0.x, v0.y); o.y = pack2(v0.z, v0.w);
  o.z = pack2(v1.x, v1.y); o.w = pack2(v1.z, v1.w);
  const int f = col >> 5, mr = col & 31, t = k >> 4, q = (k >> 3) & 1;
  size_t off = (((size_t)f * TQ + t) * 64 + q * 32 + mr) * 8;
  *(uint4*)(dst + off) = o;
}

// ---------- X1 (gemm1 A): rows (b,[feats(2);prev(16)]) -> 32-frag layout ----------
__global__ __launch_bounds__(256) void pack_x1(
    const float* __restrict__ inp, const float* __restrict__ st,
    uint16_t* __restrict__ X1) {
  const int r16 = blockIdx.x, kb = blockIdx.y;      // 72 x 32
  const int row_in = threadIdx.x >> 4, k8 = threadIdx.x & 15;
  const int row = r16 * 16 + row_in;
  const int k = kb * 128 + k8 * 8;
  int b = row / 18, c = row - b * 18;
  const float* p = (c < 2) ? (inp + (size_t)b * 8192 + (size_t)c * 4096 + k)
                           : (st + (size_t)b * 65536 + (size_t)(c - 2) * 4096 + k);
  float4 v0 = *(const float4*)p;
  float4 v1 = *(const float4*)(p + 4);
  uint4 o;
  o.x = pack2(v0.x, v0.y); o.y = pack2(v0.z, v0.w);
  o.z = pack2(v1.x, v1.y); o.w = pack2(v1.z, v1.w);
  const int f = row >> 5, mr = row & 31, t = k >> 4, q = (k >> 3) & 1;
  size_t off = (((size_t)f * TQ + t) * 64 + q * 32 + mr) * 8;
  *(uint4*)(X1 + off) = o;
}

// direct global->LDS, 16B per lane; LDS dest is wave-uniform base + lane*16
__device__ __forceinline__ void gl_lds16(const uint16_t* g, uint16_t* l) {
  __builtin_amdgcn_global_load_lds(
      (const __attribute__((address_space(1))) uint32_t*)g,
      (__attribute__((address_space(3))) uint32_t*)l, 16, 0, 0);
}

// ---------- A-streamed, B-LDS 32x32x16 GEMM (R7) ----------
// R6 lesson: acc-reg overrun -> scratch spill (WRITE_SIZE 4.3x). Keep acc<=128.
// R5 lesson: LDS total traffic (~85-128 B/cy/CU) was the cap at MfmaUtil 45%.
// R7: A-fragments are read DIRECTLY global->reg (pre-packed layout = one
// coalesced 1KB dwordx4 per frag; the 4 waves sharing wr issue identical
// addresses -> L1 serves 3/4; panel is L2-resident). Only B goes through LDS:
// per K=32 chunk LDS = stage 16KB + read 32KB = 48KB (~375-565cy) vs MFMA
// (MODE3) 128 x 8.07 = 1032cy -> MFMA-BOUND. 32x32x16 MFMA: +20% matrix
// ceiling (2495 vs 2075 TF), half the MFMA instructions.
//   MODE1: tile 192x256, waves 2x4, wave 96x64 (acc 6x16=96), KS1,
//          grid (16,6,2)=192 blocks, NCH=128 chunks.
//   MODE3: tile 256x256, waves 2x4, wave 128x64 (acc 8x16=128), KS2,
//          grid (16,4,4)=256 blocks, NCH=64 chunks.
// Pipeline (R5-proven skeleton): iter c stages B(c+2) (2 gl_lds/wave) and
// loads A(c+1)->alt reg set (2*AR dwordx4); vmcnt(2+2*AR) then guarantees
// A(c) and B(c+1) landed while current-iter loads fly; raw s_barrier (no
// drain); B read JIT from LDS with lgkmcnt(2)/(0) between the two k-halves.
// Buffer safety: stage target (c+2)&3 was read at iter c-2, barrier at c-1
// intervenes. sched_barrier(0) after each counted wait (rule 18).
template <int MODE>
__global__ __launch_bounds__(512, 2) void gemm_frag(
    const uint16_t* __restrict__ Af, const uint16_t* __restrict__ S0f,
    const uint16_t* __restrict__ S1f, uint16_t* __restrict__ D) {
  constexpr int MFR  = (MODE == 1) ? 6 : 8;    // a-frags per tile
  constexpr int AR   = (MODE == 1) ? 3 : 4;    // a-frags per wave
  constexpr int BR   = 2;                      // b-frags per wave
  constexpr int OUTC = (MODE == 1) ? 36 : 32;
  constexpr int NCH  = (MODE == 1) ? 128 : 64; // K chunks of 32
  constexpr size_t PSTRIDE = (size_t)64 * 32 * NNODE;  // MODE3 partials

  __shared__ uint16_t sB[4][16][512];          // 64 KiB, B-frags only

  const int lane = threadIdx.x & 63, wave = threadIdx.x >> 6;
  const int wr = wave >> 2, wc = wave & 3;
  int s, tBegT;
  if constexpr (MODE == 1) { s = blockIdx.z; tBegT = 0; }
  else { s = blockIdx.z & 1; tBegT = (blockIdx.z >> 1) * 128; }
  const uint16_t* __restrict__ Bf = s ? S1f : S0f;
  const int yF = blockIdx.y * MFR;   // a-frag base
  const int xF8 = blockIdx.x * 8;    // b-frag base (8 frags = 256 cols)

  // A stream pointers (per-wave; 4 waves with equal wr share -> L1)
  const uint16_t* Ap[AR];
#pragma unroll
  for (int i = 0; i < AR; ++i)
    Ap[i] = Af + ((size_t)(yF + wr * AR + i) * TQ + tBegT) * 512 +
            (size_t)lane * 8;
  // B stage pointer: wave w stages b-frag xF8+w (both k-halves per chunk)
  const uint16_t* Bp = Bf + ((size_t)(xF8 + wave) * TQ + tBegT) * 512 +
                       (size_t)lane * 8;

  floatx16 acc[AR][BR];
#pragma unroll
  for (int i = 0; i < AR; ++i)
#pragma unroll
    for (int j = 0; j < BR; ++j)
#pragma unroll
      for (int r = 0; r < 16; ++r) acc[i][j][r] = 0.f;

  auto STAGE = [&](int bi, int c) {
    gl_lds16(Bp + (size_t)(2 * c) * 512,     &sB[bi][wave * 2 + 0][0]);
    gl_lds16(Bp + (size_t)(2 * c + 1) * 512, &sB[bi][wave * 2 + 1][0]);
  };
  auto LOADA = [&](int c, bf16x8* a) {
#pragma unroll
    for (int i = 0; i < AR; ++i) {
      a[i * 2 + 0] = *(const bf16x8*)(Ap[i] + (size_t)(2 * c) * 512);
      a[i * 2 + 1] = *(const bf16x8*)(Ap[i] + (size_t)(2 * c + 1) * 512);
    }
  };
  auto COMPUTE = [&](int bi, bf16x8* a) {
    bf16x8 bR[4];  // [tt*2 + ct]; slot for b-frag g, tt = g*2+tt
    bR[0] = *(const bf16x8*)&sB[bi][(wc * 2 + 0) * 2 + 0][lane * 8];
    bR[1] = *(const bf16x8*)&sB[bi][(wc * 2 + 1) * 2 + 0][lane * 8];
    bR[2] = *(const bf16x8*)&sB[bi][(wc * 2 + 0) * 2 + 1][lane * 8];
    bR[3] = *(const bf16x8*)&sB[bi][(wc * 2 + 1) * 2 + 1][lane * 8];
    asm volatile("s_waitcnt lgkmcnt(2)" ::: "memory");
    __builtin_amdgcn_sched_barrier(0);
    __builtin_amdgcn_s_setprio(1);
#pragma unroll
    for (int rt = 0; rt < AR; ++rt)
#pragma unroll
      for (int ct = 0; ct < BR; ++ct)
        acc[rt][ct] = __builtin_amdgcn_mfma_f32_32x32x16_bf16(
            a[rt * 2 + 0], bR[ct], acc[rt][ct], 0, 0, 0);
    __builtin_amdgcn_s_setprio(0);
    asm volatile("s_waitcnt lgkmcnt(0)" ::: "memory");
    __builtin_amdgcn_sched_barrier(0);
    __builtin_amdgcn_s_setprio(1);
#pragma unroll
    for (int rt = 0; rt < AR; ++rt)
#pragma unroll
      for (int ct = 0; ct < BR; ++ct)
        acc[rt][ct] = __builtin_amdgcn_mfma_f32_32x32x16_bf16(
            a[rt * 2 + 1], bR[2 + ct], acc[rt][ct], 0, 0, 0);
    __builtin_amdgcn_s_setprio(0);
  };

  // prologue
  STAGE(0, 0);
  STAGE(1, 1);
  bf16x8 aA[2 * AR], aB[2 * AR];
  LOADA(0, aA);
  asm volatile("s_waitcnt vmcnt(0)" ::: "memory");
  __builtin_amdgcn_sched_barrier(0);
  __builtin_amdgcn_s_barrier();
  __builtin_amdgcn_sched_barrier(0);

#define GITER(J, STB, RDB, CUR, NXT)                                        \
  {                                                                         \
    int cs = c0 + (J) + 2; if (cs > NCH - 1) cs = NCH - 1;                  \
    STAGE((STB), cs);                                                       \
    int ca = c0 + (J) + 1; if (ca > NCH - 1) ca = NCH - 1;                  \
    LOADA(ca, NXT);                                                         \
    if constexpr (MODE == 1)                                                \
      asm volatile("s_waitcnt vmcnt(8)" ::: "memory");                      \
    else                                                                    \
      asm volatile("s_waitcnt vmcnt(10)" ::: "memory");                     \
    __builtin_amdgcn_sched_barrier(0);                                      \
    __builtin_amdgcn_s_barrier();                                           \
    __builtin_amdgcn_sched_barrier(0);                                      \
    COMPUTE((RDB), CUR);                                                    \
    __builtin_amdgcn_sched_barrier(0);                                      \
  }

  for (int m = 0; m < NCH / 4; ++m) {
    const int c0 = m * 4;
    GITER(0, 2, 0, aA, aB)   // MFMA chunk c0 (set A), A(c0+1)->B, B(c0+2)->buf2
    GITER(1, 3, 1, aB, aA)
    GITER(2, 0, 2, aA, aB)
    GITER(3, 1, 3, aB, aA)
  }
#undef GITER

  uint16_t* Dp = D;
  if constexpr (MODE == 3) Dp = D + (size_t)(blockIdx.z >> 1) * PSTRIDE;
  // epilogue: 32x32 C/D layout col=lane&31, row=(reg&3)+8*(reg>>2)+4*(lane>>5)
#pragma unroll
  for (int rt = 0; rt < AR; ++rt) {
    const int rbase = (yF + wr * AR + rt) * 32 + ((lane >> 5) << 2);
#pragma unroll
    for (int ct = 0; ct < BR; ++ct) {
      const int colg = (xF8 + wc * BR + ct) * 32 + (lane & 31);
#pragma unroll
      for (int reg = 0; reg < 16; ++reg) {
        int rowg = rbase + (reg & 3) + ((reg >> 2) << 3);
        int b, c, jj;
        if constexpr (MODE == 1) {
          b = rowg / 18; c = rowg - 18 * b;
          jj = (c < 2) ? (2 * s + c) : (4 + 16 * s + (c - 2));
        } else {
          b = rowg >> 4; c = rowg & 15; jj = 16 * s + c;
        }
        Dp[(size_t)(b * OUTC + jj) * NNODE + colg] = f2b(acc[rt][ct][reg]);
      }
    }
  }
}

// ---------- stage2: r,u gates; X2 = r*prev -> 32-frag layout via LDS ----------
__global__ __launch_bounds__(256) void stage2(
    const uint16_t* __restrict__ P1, const float* __restrict__ state,
    const float* __restrict__ rk, const float* __restrict__ uk,
    uint16_t* __restrict__ X2f, float* __restrict__ U) {
  __shared__ float s_rk[576], s_uk[576];
  __shared__ uint16_t s_x2[16 * 264];  // [k][i], padded stride
  for (int i = threadIdx.x; i < 576; i += 256) { s_rk[i] = rk[i]; s_uk[i] = uk[i]; }
  __syncthreads();
  const int b = blockIdx.x >> 4, nb = blockIdx.x & 15;
  const int i = threadIdx.x;
  const int n = nb * 256 + i;
  float hs[36];
  const uint16_t* p = P1 + (size_t)b * 36 * NNODE + n;
#pragma unroll
  for (int j = 0; j < 36; ++j)
    hs[j] = b2f(p[(size_t)j * NNODE]);   // gemm1 is full-K now (no partials)
  float ar[16], au[16];
#pragma unroll
  for (int k = 0; k < 16; ++k) { ar[k] = 0.f; au[k] = 0.f; }
#pragma unroll
  for (int j = 0; j < 36; ++j) {
    float h = hs[j];
#pragma unroll
    for (int k = 0; k < 16; ++k) {
      ar[k] += h * s_rk[j * 16 + k];
      au[k] += h * s_uk[j * 16 + k];
    }
  }
  const float* sp = state + (size_t)b * 65536 + n;
#pragma unroll
  for (int k = 0; k < 16; ++k) {
    float r = 1.f / (1.f + __expf(-ar[k]));
    float uu = 1.f / (1.f + __expf(-au[k]));
    float prev = sp[(size_t)k * NNODE];
    s_x2[k * 264 + i] = f2b(r * prev);
    U[(size_t)(b * 16 + k) * NNODE + n] = uu;
  }
  __syncthreads();
  // flush 16 rows x 256 n to 32-frag layout: row=b*16+kk -> frag b>>1,
  // mr=(b&1)*16+kk; k-dim = n: t=n>>4, q=(n>>3)&1, 8 consecutive n = j.
  const int fq = b >> 1, mro = (b & 1) * 16;
#pragma unroll
  for (int rr = 0; rr < 2; ++rr) {
    int fid = rr * 256 + i;
    int kk = fid & 15, qq = (fid >> 4) & 3, tl = fid >> 6;
    int n0 = nb * 256 + tl * 32 + qq * 8;
    int t = n0 >> 4, q = (n0 >> 3) & 1;
    size_t off = (((size_t)fq * TQ + t) * 64 + q * 32 + (mro + kk)) * 8;
    *(uint4*)(X2f + off) = *(const uint4*)&s_x2[kk * 264 + tl * 32 + qq * 8];
  }
}

// ---------- stage4: c = tanh([h;D3]*ck); z = u*prev + (1-u)*c ----------
// OUTPUT LAYOUT: z is (B, N, U) reshaped -> out[b*65536 + n*16 + k]
__global__ __launch_bounds__(256) void stage4(
    const uint16_t* __restrict__ P1, const uint16_t* __restrict__ P3,
    const float* __restrict__ U, const float* __restrict__ state,
    const float* __restrict__ ck, float* __restrict__ out) {
  constexpr size_t PS3 = (size_t)64 * 32 * NNODE;
  __shared__ float s_ck[576];
  for (int i = threadIdx.x; i < 576; i += 256) s_ck[i] = ck[i];
  __syncthreads();
  int idx = blockIdx.x * 256 + threadIdx.x;
  int b = idx >> 12, n = idx & 4095;
  float hv[36];
  const uint16_t* p1 = P1 + (size_t)b * 36 * NNODE + n;
#pragma unroll
  for (int j = 0; j < 4; ++j)
    hv[j] = b2f(p1[(size_t)j * NNODE]);           // full-K gemm1
  const uint16_t* p3 = P3 + (size_t)b * 32 * NNODE + n;
#pragma unroll
  for (int j = 0; j < 32; ++j)
    hv[4 + j] = b2f(p3[(size_t)j * NNODE]) + b2f(p3[PS3 + (size_t)j * NNODE]);
  float ac[16];
#pragma unroll
  for (int k = 0; k < 16; ++k) ac[k] = 0.f;
#pragma unroll
  for (int j = 0; j < 36; ++j) {
    float h = hv[j];
#pragma unroll
    for (int k = 0; k < 16; ++k) ac[k] += h * s_ck[j * 16 + k];
  }
  const float* sp = state + (size_t)b * 65536 + n;
  const float* up = U + (size_t)b * 16 * NNODE + n;
  float z[16];
#pragma unroll
  for (int k = 0; k < 16; ++k) {
    float e = __expf(2.f * ac[k]);
    float c = 1.f - 2.f / (e + 1.f);  // tanh, saturates at +/-inf
    float uu = up[(size_t)k * NNODE];
    float prev = sp[(size_t)k * NNODE];
    z[k] = uu * prev + (1.f - uu) * c;
  }
  float4* po = (float4*)(out + (size_t)b * 65536 + (size_t)n * 16);
#pragma unroll
  for (int k4 = 0; k4 < 4; ++k4)
    po[k4] = make_float4(z[k4 * 4], z[k4 * 4 + 1], z[k4 * 4 + 2], z[k4 * 4 + 3]);
}

extern "C" void kernel_launch(void* const* d_in, const int* in_sizes, int n_in,
                              void* d_out, int out_size, void* d_ws, size_t ws_size,
                              hipStream_t stream) {
  const float* inputs = (const float*)d_in[0];
  const float* state = (const float*)d_in[1];
  const float* s0 = (const float*)d_in[2];
  const float* s1 = (const float*)d_in[3];
  const float* rk = (const float*)d_in[4];
  const float* uk = (const float*)d_in[5];
  const float* ck = (const float*)d_in[6];
  float* out = (float*)d_out;
  char* ws = (char*)d_ws;

  // workspace layout (bytes); X2f aliases X1f (dead after gemm1)
  uint16_t* S0f = (uint16_t*)(ws);                  // 33,554,432
  uint16_t* S1f = (uint16_t*)(ws + 33554432);       // 33,554,432
  uint16_t* X1f = (uint16_t*)(ws + 67108864);       // 9,437,184
  uint16_t* X2f = (uint16_t*)(ws + 67108864);       // 8,388,608 (alias)
  uint16_t* P1 = (uint16_t*)(ws + 76546048);        // 18,874,368 (full-K sums)
  float* U = (float*)(ws + 95420416);               // 16,777,216
  uint16_t* P3 = (uint16_t*)(ws + 112197632);       // 2 x 16,777,216 (KS2 partials)
  // total 145,752,064 bytes (< previous 164.6 MB footprint)

  cvt_supports<<<dim3(256, 32, 2), 256, 0, stream>>>(s0, s1, S0f, S1f);
  pack_x1<<<dim3(72, 32), 256, 0, stream>>>(inputs, state, X1f);
  gemm_frag<1><<<dim3(16, 6, 2), 512, 0, stream>>>(X1f, S0f, S1f, P1);
  stage2<<<1024, 256, 0, stream>>>(P1, state, rk, uk, X2f, U);
  gemm_frag<3><<<dim3(16, 4, 4), 512, 0, stream>>>(X2f, S0f, S1f, P3);
  stage4<<<1024, 256, 0, stream>>>(P1, P3, U, state, ck, out);
}

// Round 8
// 352.482 us; speedup vs baseline: 1.2462x; 1.1383x over previous
//
#include <hip/hip_runtime.h>
#include <cstdint>

#define KDIM 4096
#define NNODE 4096
#define TSTEPS 128            // K-steps of 32 over KDIM

typedef __bf16 bf16x8 __attribute__((ext_vector_type(8)));
typedef float floatx4 __attribute__((ext_vector_type(4)));

__device__ __forceinline__ uint16_t f2b(float f) {
  union { float f; uint32_t u; } v; v.f = f;
  uint32_t u = v.u;
  return (uint16_t)((u + 0x7FFFu + ((u >> 16) & 1u)) >> 16);  // RNE
}
__device__ __forceinline__ float b2f(uint16_t h) {
  union { uint32_t u; float f; } v; v.u = ((uint32_t)h) << 16; return v.f;
}
__device__ __forceinline__ uint32_t pack2(float a, float b) {
  return (uint32_t)f2b(a) | ((uint32_t)f2b(b) << 16);
}

// Fragment layout (both GEMM operands): frag[f16][t][lane][8] where
// elem = M[f16*16 + mr][t*32 + q*8 + j], lane = q*16 + mr.
// A wave's fragment load = base + lane*16B -> one fully-coalesced 1KB dwordx4.

// ---------- supports: fp32 row-major -> bf16 fragment layout ----------
// R8: wave-per-granule. lane q*16+mr reads 32B of row c16*16+mr at k=t*32+q*8
// (4 lanes/row -> 128B contiguous read segments); wave writes one contiguous
// 1KB granule (lane*16B). Output bytes identical to the old packer
// (t*32+q*8 == kb*128+k8*8), only the store pattern is now coalesced.
__global__ __launch_bounds__(256) void cvt_supports(
    const float* __restrict__ s0, const float* __restrict__ s1,
    uint16_t* __restrict__ d0, uint16_t* __restrict__ d1) {
  const float* src = blockIdx.z ? s1 : s0;
  uint16_t* dst = blockIdx.z ? d1 : d0;
  const int c16 = blockIdx.x;                         // 256 col-groups of 16
  const int t = blockIdx.y * 4 + (threadIdx.x >> 6);  // granule t (0..127)
  const int lane = threadIdx.x & 63;
  const int mr = lane & 15, q = lane >> 4;
  const float* p = src + (size_t)(c16 * 16 + mr) * KDIM + t * 32 + q * 8;
  float4 v0 = *(const float4*)p;
  float4 v1 = *(const float4*)(p + 4);
  uint4 o;
  o.x = pack2(v0.x, v0.y); o.y = pack2(v0.z, v0.w);
  o.z = pack2(v1.x, v1.y); o.w = pack2(v1.z, v1.w);
  *(uint4*)(dst + ((size_t)(c16 * 128 + t)) * 512 + (size_t)lane * 8) = o;
}

// ---------- X1 (gemm1 A): rows (b,[feats(2);prev(16)]) -> fragment layout ----------
__global__ __launch_bounds__(256) void pack_x1(
    const float* __restrict__ inp, const float* __restrict__ st,
    uint16_t* __restrict__ X1) {
  const int r16 = blockIdx.x;                         // 72 row-groups of 16
  const int t = blockIdx.y * 4 + (threadIdx.x >> 6);  // granule t (0..127)
  const int lane = threadIdx.x & 63;
  const int mr = lane & 15, q = lane >> 4;
  const int row = r16 * 16 + mr;
  int b = row / 18, c = row - b * 18;
  const float* p = (c < 2) ? (inp + (size_t)b * 8192 + (size_t)c * 4096)
                           : (st + (size_t)b * 65536 + (size_t)(c - 2) * 4096);
  p += t * 32 + q * 8;
  float4 v0 = *(const float4*)p;
  float4 v1 = *(const float4*)(p + 4);
  uint4 o;
  o.x = pack2(v0.x, v0.y); o.y = pack2(v0.z, v0.w);
  o.z = pack2(v1.x, v1.y); o.w = pack2(v1.z, v1.w);
  *(uint4*)(X1 + ((size_t)(r16 * 128 + t)) * 512 + (size_t)lane * 8) = o;
}

// direct global->LDS, 16B per lane; LDS dest is wave-uniform base + lane*16
__device__ __forceinline__ void gl_lds16(const uint16_t* g, uint16_t* l) {
  __builtin_amdgcn_global_load_lds(
      (const __attribute__((address_space(1))) uint32_t*)g,
      (__attribute__((address_space(3))) uint32_t*)l, 16, 0, 0);
}

// ---------- 1-block-per-CU full-K fragment GEMM (R5 structure, proven) ----------
// R7 post-mortem: A-streaming global->reg quadruplicated A traffic through
// L1/L2 (waves sharing wr don't dedup concurrent misses) -> L2-BW+latency
// bound, MfmaUtil 26%. REVERTED to the R5 structure (72us/gemm, MfmaUtil 45%,
// LDS-read-throughput-bound at ~85-128 B/cy/CU shared per CU):
// ONE 512-thread block per CU, grids exactly 256, full K=4096:
//   MODE1: tile 144x256 (1152=8x144), waves 1x8, wave tile 144x32.
//   MODE3: tile 128x256, waves 2x4, wave tile 64x64.
// 4 LDS buffers, depth-3 counted vmcnt staging, register double-buffer with
// counted lgkmcnt (reads issued a full iter ahead of their MFMAs).
template <int MODE>
__global__ __launch_bounds__(512, 2) void gemm_frag(
    const uint16_t* __restrict__ Af, const uint16_t* __restrict__ S0f,
    const uint16_t* __restrict__ S1f, uint16_t* __restrict__ D) {
  constexpr int CPB   = (MODE == 1) ? 18 : 16;
  constexpr int OUTC  = (MODE == 1) ? 36 : 32;
  constexpr int MFR   = (MODE == 1) ? 9 : 8;   // A frag-rows per tile
  constexpr int WM    = (MODE == 1) ? 1 : 2;   // wave grid M
  constexpr int WN    = 8 / WM;                // wave grid N
  constexpr int AR    = MFR / WM;              // a-frags per wave (9 / 4)
  constexpr int BR    = 16 / WN;               // b-frags per wave (2 / 4)
  constexpr int NREAL = MFR + 16;              // 25 / 24
  constexpr int SLOTS = (NREAL + 7) & ~7;      // 32 / 24
  constexpr int LPW   = SLOTS / 8;             // loads per wave (4 / 3)
  constexpr int NCH   = TSTEPS;                // 128 chunks of K=32 (full K)

  __shared__ uint16_t sAB[4][SLOTS][512];      // 128 KiB / 96 KiB

  const int lane = threadIdx.x & 63, wave = threadIdx.x >> 6;
  const int wr = wave / WN, wc = wave % WN;
  const int s = blockIdx.z;
  const uint16_t* __restrict__ Bf = s ? S1f : S0f;
  const int yF = blockIdx.y * MFR;   // A frag-row base
  const int xF = blockIdx.x * 16;    // B frag-col base (256 cols)

  // staging: wave stages slots [wave*LPW, wave*LPW+LPW).
  // slot < MFR: A frag yF+slot; slot < NREAL: B frag xF+slot-MFR;
  // else pad -> duplicate A frag yF (idempotent, L1-hot).
  const uint16_t* Gp[LPW];
#pragma unroll
  for (int i = 0; i < LPW; ++i) {
    int sid = wave * LPW + i;
    const uint16_t* base;
    int fr;
    if (sid < MFR)        { base = Af; fr = yF + sid; }
    else if (sid < NREAL) { base = Bf; fr = xF + sid - MFR; }
    else                  { base = Af; fr = yF; }
    Gp[i] = base + (size_t)fr * (TSTEPS * 512) + (size_t)lane * 8;
  }

  floatx4 acc[AR][BR];
#pragma unroll
  for (int i = 0; i < AR; ++i)
#pragma unroll
    for (int j = 0; j < BR; ++j) acc[i][j] = (floatx4){0.f, 0.f, 0.f, 0.f};

  auto STAGE = [&](int bi, int c) {
    uint16_t* l = &sAB[bi][wave * LPW][0];
    const size_t off = (size_t)c * 512;
#pragma unroll
    for (int i = 0; i < LPW; ++i)
      gl_lds16(Gp[i] + off, l + (size_t)i * 512);
  };

  auto LDREG = [&](int bi, bf16x8* a, bf16x8* b) {
    const uint16_t* base = &sAB[bi][0][lane * 8];
#pragma unroll
    for (int rt = 0; rt < AR; ++rt)
      a[rt] = *(const bf16x8*)(base + (size_t)(wr * AR + rt) * 512);
#pragma unroll
    for (int ct = 0; ct < BR; ++ct)
      b[ct] = *(const bf16x8*)(base + (size_t)(MFR + wc * BR + ct) * 512);
  };

  auto MFMAALL = [&](bf16x8* a, bf16x8* b) {
    __builtin_amdgcn_s_setprio(1);
#pragma unroll
    for (int rt = 0; rt < AR; ++rt)
#pragma unroll
      for (int ct = 0; ct < BR; ++ct)
        acc[rt][ct] = __builtin_amdgcn_mfma_f32_16x16x32_bf16(
            a[rt], b[ct], acc[rt][ct], 0, 0, 0);
    __builtin_amdgcn_s_setprio(0);
  };

  auto waitVM = [&] {  // chunk c+1 landed; 2 chunks (2*LPW loads) in flight
    if constexpr (MODE == 1) asm volatile("s_waitcnt vmcnt(8)" ::: "memory");
    else                     asm volatile("s_waitcnt vmcnt(6)" ::: "memory");
  };
  auto waitLG = [&] {  // previous chunk's ds_reads done; current LGK in flight
    if constexpr (MODE == 1) asm volatile("s_waitcnt lgkmcnt(11)" ::: "memory");
    else                     asm volatile("s_waitcnt lgkmcnt(8)" ::: "memory");
  };

  // prologue: chunks 0,1,2 staged; chunk 0 -> regset A
  STAGE(0, 0);
  STAGE(1, 1);
  STAGE(2, 2);
  waitVM();
  __builtin_amdgcn_sched_barrier(0);
  __builtin_amdgcn_s_barrier();
  __builtin_amdgcn_sched_barrier(0);
  bf16x8 aA[AR], bA[BR], aB[AR], bB[BR];
  LDREG(0, aA, bA);

#define GITER(J, SB, RB, CA, CB, NA, NB)                                    \
  {                                                                         \
    int cl = c0 + 3 + (J);                                                  \
    if (cl > NCH - 1) cl = NCH - 1; /* clamped redundant tail stage */      \
    STAGE((SB), cl);                                                        \
    waitVM();                                                               \
    __builtin_amdgcn_sched_barrier(0);                                      \
    __builtin_amdgcn_s_barrier();                                           \
    __builtin_amdgcn_sched_barrier(0);                                      \
    LDREG((RB), NA, NB);                                                    \
    waitLG();                                                               \
    __builtin_amdgcn_sched_barrier(0);                                      \
    MFMAALL(CA, CB);                                                        \
    __builtin_amdgcn_sched_barrier(0);                                      \
  }

  for (int m = 0; m < NCH / 4; ++m) {
    const int c0 = m * 4;
    GITER(0, 3, 1, aA, bA, aB, bB)   // MFMA chunk c0   (A), load c0+1 -> B
    GITER(1, 0, 2, aB, bB, aA, bA)   // MFMA chunk c0+1 (B), load c0+2 -> A
    GITER(2, 1, 3, aA, bA, aB, bB)
    GITER(3, 2, 0, aB, bB, aA, bA)
  }
#undef GITER

  // epilogue: C/D layout col=lane&15, row=(lane>>4)*4+reg; D row-major bf16
#pragma unroll
  for (int rt = 0; rt < AR; ++rt) {
#pragma unroll
    for (int r = 0; r < 4; ++r) {
      int rowg = (yF + wr * AR + rt) * 16 + (lane >> 4) * 4 + r;
      int b = rowg / CPB, c = rowg - b * CPB;
      int jj;
      if (MODE == 1) jj = (c < 2) ? (2 * s + c) : (4 + 16 * s + (c - 2));
      else jj = 16 * s + c;
      uint16_t* drow = D + (size_t)(b * OUTC + jj) * NNODE;
#pragma unroll
      for (int ct = 0; ct < BR; ++ct) {
        int colg = xF * 16 + (wc * BR + ct) * 16 + (lane & 15);
        drow[colg] = f2b(acc[rt][ct][r]);
      }
    }
  }
}

// ---------- stage2: r,u gates; X2 = r*prev -> fragment layout via LDS transpose ----------
__global__ __launch_bounds__(256) void stage2(
    const uint16_t* __restrict__ P1, const float* __restrict__ state,
    const float* __restrict__ rk, const float* __restrict__ uk,
    uint16_t* __restrict__ X2f, float* __restrict__ U) {
  __shared__ float s_rk[576], s_uk[576];
  __shared__ uint16_t s_x2[16 * 264];  // [k][i], padded stride (264) vs 256
  for (int i = threadIdx.x; i < 576; i += 256) { s_rk[i] = rk[i]; s_uk[i] = uk[i]; }
  __syncthreads();
  const int b = blockIdx.x >> 4, nb = blockIdx.x & 15;
  const int i = threadIdx.x;
  const int n = nb * 256 + i;
  float hs[36];
  const uint16_t* p = P1 + (size_t)b * 36 * NNODE + n;
#pragma unroll
  for (int j = 0; j < 36; ++j)
    hs[j] = b2f(p[(size_t)j * NNODE]);   // full sums (no split-K partials)
  float ar[16], au[16];
#pragma unroll
  for (int k = 0; k < 16; ++k) { ar[k] = 0.f; au[k] = 0.f; }
#pragma unroll
  for (int j = 0; j < 36; ++j) {
    float h = hs[j];
#pragma unroll
    for (int k = 0; k < 16; ++k) {
      ar[k] += h * s_rk[j * 16 + k];
      au[k] += h * s_uk[j * 16 + k];
    }
  }
  const float* sp = state + (size_t)b * 65536 + n;
#pragma unroll
  for (int k = 0; k < 16; ++k) {
    float r = 1.f / (1.f + __expf(-ar[k]));
    float uu = 1.f / (1.f + __expf(-au[k]));
    float prev = sp[(size_t)k * NNODE];
    s_x2[k * 264 + i] = f2b(r * prev);
    U[(size_t)(b * 16 + k) * NNODE + n] = uu;
  }
  __syncthreads();
  // flush 4096 bf16 (16 k x 256 n) to fragment layout: contiguous 8KB region.
  uint16_t* region = X2f + ((size_t)b * 128 + nb * 8) * 512;
#pragma unroll
  for (int rr = 0; rr < 2; ++rr) {
    int fid = rr * 256 + i;
    int kk = fid & 15, qq = (fid >> 4) & 3, tl = fid >> 6;
    uint4 v = *(const uint4*)&s_x2[kk * 264 + tl * 32 + qq * 8];
    *(uint4*)(region + (size_t)fid * 8) = v;
  }
}

// ---------- stage4: c = tanh([h;D3]*ck); z = u*prev + (1-u)*c ----------
// OUTPUT LAYOUT: z is (B, N, U) reshaped -> out[b*65536 + n*16 + k]
__global__ __launch_bounds__(256) void stage4(
    const uint16_t* __restrict__ P1, const uint16_t* __restrict__ P3,
    const float* __restrict__ U, const float* __restrict__ state,
    const float* __restrict__ ck, float* __restrict__ out) {
  __shared__ float s_ck[576];
  for (int i = threadIdx.x; i < 576; i += 256) s_ck[i] = ck[i];
  __syncthreads();
  int idx = blockIdx.x * 256 + threadIdx.x;
  int b = idx >> 12, n = idx & 4095;
  float hv[36];
  const uint16_t* p1 = P1 + (size_t)b * 36 * NNODE + n;
#pragma unroll
  for (int j = 0; j < 4; ++j)
    hv[j] = b2f(p1[(size_t)j * NNODE]);
  const uint16_t* p3 = P3 + (size_t)b * 32 * NNODE + n;
#pragma unroll
  for (int j = 0; j < 32; ++j)
    hv[4 + j] = b2f(p3[(size_t)j * NNODE]);
  float ac[16];
#pragma unroll
  for (int k = 0; k < 16; ++k) ac[k] = 0.f;
#pragma unroll
  for (int j = 0; j < 36; ++j) {
    float h = hv[j];
#pragma unroll
    for (int k = 0; k < 16; ++k) ac[k] += h * s_ck[j * 16 + k];
  }
  const float* sp = state + (size_t)b * 65536 + n;
  const float* up = U + (size_t)b * 16 * NNODE + n;
  float z[16];
#pragma unroll
  for (int k = 0; k < 16; ++k) {
    float e = __expf(2.f * ac[k]);
    float c = 1.f - 2.f / (e + 1.f);  // tanh, saturates at +/-inf
    float uu = up[(size_t)k * NNODE];
    float prev = sp[(size_t)k * NNODE];
    z[k] = uu * prev + (1.f - uu) * c;
  }
  float4* po = (float4*)(out + (size_t)b * 65536 + (size_t)n * 16);
#pragma unroll
  for (int k4 = 0; k4 < 4; ++k4)
    po[k4] = make_float4(z[k4 * 4], z[k4 * 4 + 1], z[k4 * 4 + 2], z[k4 * 4 + 3]);
}

extern "C" void kernel_launch(void* const* d_in, const int* in_sizes, int n_in,
                              void* d_out, int out_size, void* d_ws, size_t ws_size,
                              hipStream_t stream) {
  const float* inputs = (const float*)d_in[0];
  const float* state = (const float*)d_in[1];
  const float* s0 = (const float*)d_in[2];
  const float* s1 = (const float*)d_in[3];
  const float* rk = (const float*)d_in[4];
  const float* uk = (const float*)d_in[5];
  const float* ck = (const float*)d_in[6];
  float* out = (float*)d_out;
  char* ws = (char*)d_ws;

  // workspace layout (bytes); X2f aliases X1f (dead after gemm1)
  uint16_t* S0f = (uint16_t*)(ws);                  // 33,554,432
  uint16_t* S1f = (uint16_t*)(ws + 33554432);       // 33,554,432
  uint16_t* X1f = (uint16_t*)(ws + 67108864);       // 9,437,184   (1152 x 4096 bf16, frag)
  uint16_t* X2f = (uint16_t*)(ws + 67108864);       // 8,388,608   (aliases X1f, frag)
  uint16_t* P1 = (uint16_t*)(ws + 76546048);        // 18,874,368  (full sums, no split-K)
  float* U = (float*)(ws + 114294784);              // 16,777,216
  uint16_t* P3 = (uint16_t*)(ws + 131072000);       // 16,777,216  (full sums)
  // total within 164,626,432 bytes

  cvt_supports<<<dim3(256, 32, 2), 256, 0, stream>>>(s0, s1, S0f, S1f);
  pack_x1<<<dim3(72, 32), 256, 0, stream>>>(inputs, state, X1f);
  gemm_frag<1><<<dim3(16, 8, 2), 512, 0, stream>>>(X1f, S0f, S1f, P1);
  stage2<<<1024, 256, 0, stream>>>(P1, state, rk, uk, X2f, U);
  gemm_frag<3><<<dim3(16, 8, 2), 512, 0, stream>>>(X2f, S0f, S1f, P3);
  stage4<<<1024, 256, 0, stream>>>(P1, P3, U, state, ck, out);
}

// Round 9
// 342.359 us; speedup vs baseline: 1.2831x; 1.0296x over previous
//
#include <hip/hip_runtime.h>
#include <cstdint>

#define KDIM 4096
#define NNODE 4096
#define TSTEPS 128            // K-steps of 32 over KDIM

typedef __bf16 bf16x8 __attribute__((ext_vector_type(8)));
typedef float floatx4 __attribute__((ext_vector_type(4)));

__device__ __forceinline__ uint16_t f2b(float f) {
  union { float f; uint32_t u; } v; v.f = f;
  uint32_t u = v.u;
  return (uint16_t)((u + 0x7FFFu + ((u >> 16) & 1u)) >> 16);  // RNE
}
__device__ __forceinline__ float b2f(uint16_t h) {
  union { uint32_t u; float f; } v; v.u = ((uint32_t)h) << 16; return v.f;
}
__device__ __forceinline__ uint32_t pack2(float a, float b) {
  return (uint32_t)f2b(a) | ((uint32_t)f2b(b) << 16);
}

// Fragment layout (both GEMM operands): frag[f16][t][lane][8] where
// elem = M[f16*16 + mr][t*32 + q*8 + j], lane = q*16 + mr.
// A wave's fragment load = base + lane*16B -> one fully-coalesced 1KB dwordx4.

// ---------- fused packer: supports + X1 -> fragment layout (one dispatch) ----------
// wave-per-granule; lane q*16+mr reads 32B of its row at k=t*32+q*8; wave
// writes one contiguous 1KB granule. z=0,1: supports; z=2: X1 (72 x-blocks).
__global__ __launch_bounds__(256) void pack_all(
    const float* __restrict__ inp, const float* __restrict__ st,
    const float* __restrict__ s0, const float* __restrict__ s1,
    uint16_t* __restrict__ X1, uint16_t* __restrict__ d0,
    uint16_t* __restrict__ d1) {
  const int t = blockIdx.y * 4 + (threadIdx.x >> 6);  // granule t (0..127)
  const int lane = threadIdx.x & 63;
  const int mr = lane & 15, q = lane >> 4;
  const float* p;
  uint16_t* dst;
  if (blockIdx.z < 2) {
    const float* src = blockIdx.z ? s1 : s0;
    uint16_t* d = blockIdx.z ? d1 : d0;
    const int c16 = blockIdx.x;                       // 256 col-groups of 16
    p = src + (size_t)(c16 * 16 + mr) * KDIM + t * 32 + q * 8;
    dst = d + ((size_t)(c16 * 128 + t)) * 512 + (size_t)lane * 8;
  } else {
    const int r16 = blockIdx.x;                       // 72 row-groups of 16
    if (r16 >= 72) return;
    const int row = r16 * 16 + mr;
    int b = row / 18, c = row - b * 18;
    const float* pb = (c < 2) ? (inp + (size_t)b * 8192 + (size_t)c * 4096)
                              : (st + (size_t)b * 65536 + (size_t)(c - 2) * 4096);
    p = pb + t * 32 + q * 8;
    dst = X1 + ((size_t)(r16 * 128 + t)) * 512 + (size_t)lane * 8;
  }
  float4 v0 = *(const float4*)p;
  float4 v1 = *(const float4*)(p + 4);
  uint4 o;
  o.x = pack2(v0.x, v0.y); o.y = pack2(v0.z, v0.w);
  o.z = pack2(v1.x, v1.y); o.w = pack2(v1.z, v1.w);
  *(uint4*)dst = o;
}

// direct global->LDS, 16B per lane; LDS dest is wave-uniform base + lane*16
__device__ __forceinline__ void gl_lds16(const uint16_t* g, uint16_t* l) {
  __builtin_amdgcn_global_load_lds(
      (const __attribute__((address_space(1))) uint32_t*)g,
      (__attribute__((address_space(3))) uint32_t*)l, 16, 0, 0);
}

// ---------- 1-block-per-CU fragment GEMM (R9) ----------
// MODE1 (unchanged R8, proven 75us): tile 144x256, waves 1x8, wave 144x32,
//   full K. LDS-read-bound cap ~45% (A-frags duplicated across the 8 waves).
// MODE3 (NEW fat wave): tile 256x256, waves 2x4, wave 128x64,
//   acc[8][4] = 128 f32 = EXACTLY the AGPR bank (R4-proven no-spill; R6's
//   spill was acc=144 > 128 AGPRs). 43.7 FLOP/LDS-byte: per chunk MFMA
//   1241cy > LDS reads 96KB/85 = 1129cy -> MFMA-bound for the first time.
//   KS2 -> grid (16,4,4) = exactly 256 blocks; LDS 4 x 32KB = 128KB.
// Both: depth-3 counted vmcnt(8) staging; register double-buffer with counted
// lgkmcnt (reads issued a full iter ahead of their MFMAs); raw s_barrier.
template <int MODE>
__global__ __launch_bounds__(512, 2) void gemm_frag(
    const uint16_t* __restrict__ Af, const uint16_t* __restrict__ S0f,
    const uint16_t* __restrict__ S1f, uint16_t* __restrict__ D) {
  constexpr int CPB   = (MODE == 1) ? 18 : 16;
  constexpr int OUTC  = (MODE == 1) ? 36 : 32;
  constexpr int MFR   = (MODE == 1) ? 9 : 16;  // A frag-rows per tile
  constexpr int WM    = (MODE == 1) ? 1 : 2;   // wave grid M
  constexpr int WN    = 8 / WM;                // wave grid N
  constexpr int AR    = MFR / WM;              // a-frags per wave (9 / 8)
  constexpr int BR    = 16 / WN;               // b-frags per wave (2 / 4)
  constexpr int NREAL = MFR + 16;              // 25 / 32
  constexpr int SLOTS = 32;                    // padded to 32 both modes
  constexpr int LPW   = SLOTS / 8;             // 4 loads per wave
  constexpr int KSP   = (MODE == 1) ? 1 : 2;   // split-K factor
  constexpr int NCH   = TSTEPS / KSP;          // 128 / 64 chunks of K=32
  constexpr size_t PSTRIDE = (size_t)64 * OUTC * NNODE;

  __shared__ uint16_t sAB[4][SLOTS][512];      // 128 KiB

  const int lane = threadIdx.x & 63, wave = threadIdx.x >> 6;
  const int wr = wave / WN, wc = wave % WN;
  int s, ks;
  if constexpr (MODE == 1) { s = blockIdx.z; ks = 0; }
  else { s = blockIdx.z & 1; ks = blockIdx.z >> 1; }
  const int tBeg = ks * NCH;
  const uint16_t* __restrict__ Bf = s ? S1f : S0f;
  const int yF = blockIdx.y * MFR;   // A frag-row base
  const int xF = blockIdx.x * 16;    // B frag-col base (256 cols)

  // staging: wave stages slots [wave*LPW, wave*LPW+LPW).
  // slot < MFR: A frag yF+slot; slot < NREAL: B frag xF+slot-MFR;
  // else pad -> duplicate A frag yF (idempotent, L1-hot; MODE1 only).
  const uint16_t* Gp[LPW];
#pragma unroll
  for (int i = 0; i < LPW; ++i) {
    int sid = wave * LPW + i;
    const uint16_t* base;
    int fr;
    if (sid < MFR)        { base = Af; fr = yF + sid; }
    else if (sid < NREAL) { base = Bf; fr = xF + sid - MFR; }
    else                  { base = Af; fr = yF; }
    Gp[i] = base + (size_t)fr * (TSTEPS * 512) + (size_t)tBeg * 512 +
            (size_t)lane * 8;
  }

  floatx4 acc[AR][BR];
#pragma unroll
  for (int i = 0; i < AR; ++i)
#pragma unroll
    for (int j = 0; j < BR; ++j) acc[i][j] = (floatx4){0.f, 0.f, 0.f, 0.f};

  auto STAGE = [&](int bi, int c) {
    uint16_t* l = &sAB[bi][wave * LPW][0];
    const size_t off = (size_t)c * 512;
#pragma unroll
    for (int i = 0; i < LPW; ++i)
      gl_lds16(Gp[i] + off, l + (size_t)i * 512);
  };

  auto LDREG = [&](int bi, bf16x8* a, bf16x8* b) {
    const uint16_t* base = &sAB[bi][0][lane * 8];
#pragma unroll
    for (int rt = 0; rt < AR; ++rt)
      a[rt] = *(const bf16x8*)(base + (size_t)(wr * AR + rt) * 512);
#pragma unroll
    for (int ct = 0; ct < BR; ++ct)
      b[ct] = *(const bf16x8*)(base + (size_t)(MFR + wc * BR + ct) * 512);
  };

  auto MFMAALL = [&](bf16x8* a, bf16x8* b) {
    __builtin_amdgcn_s_setprio(1);
#pragma unroll
    for (int rt = 0; rt < AR; ++rt)
#pragma unroll
      for (int ct = 0; ct < BR; ++ct)
        acc[rt][ct] = __builtin_amdgcn_mfma_f32_16x16x32_bf16(
            a[rt], b[ct], acc[rt][ct], 0, 0, 0);
    __builtin_amdgcn_s_setprio(0);
  };

  auto waitVM = [&] {  // chunk c+1 landed; 2 chunks (2*LPW = 8 loads) in flight
    asm volatile("s_waitcnt vmcnt(8)" ::: "memory");
  };
  auto waitLG = [&] {  // previous chunk's ds_reads done; current set in flight
    if constexpr (MODE == 1) asm volatile("s_waitcnt lgkmcnt(11)" ::: "memory");
    else                     asm volatile("s_waitcnt lgkmcnt(12)" ::: "memory");
  };

  // prologue: chunks 0,1,2 staged; chunk 0 -> regset A
  STAGE(0, 0);
  STAGE(1, 1);
  STAGE(2, 2);
  waitVM();
  __builtin_amdgcn_sched_barrier(0);
  __builtin_amdgcn_s_barrier();
  __builtin_amdgcn_sched_barrier(0);
  bf16x8 aA[AR], bA[BR], aB[AR], bB[BR];
  LDREG(0, aA, bA);

#define GITER(J, SB, RB, CA, CB, NA, NB)                                    \
  {                                                                         \
    int cl = c0 + 3 + (J);                                                  \
    if (cl > NCH - 1) cl = NCH - 1; /* clamped redundant tail stage */      \
    STAGE((SB), cl);                                                        \
    waitVM();                                                               \
    __builtin_amdgcn_sched_barrier(0);                                      \
    __builtin_amdgcn_s_barrier();                                           \
    __builtin_amdgcn_sched_barrier(0);                                      \
    LDREG((RB), NA, NB);                                                    \
    waitLG();                                                               \
    __builtin_amdgcn_sched_barrier(0);                                      \
    MFMAALL(CA, CB);                                                        \
    __builtin_amdgcn_sched_barrier(0);                                      \
  }

  for (int m = 0; m < NCH / 4; ++m) {
    const int c0 = m * 4;
    GITER(0, 3, 1, aA, bA, aB, bB)   // MFMA chunk c0   (A), load c0+1 -> B
    GITER(1, 0, 2, aB, bB, aA, bA)   // MFMA chunk c0+1 (B), load c0+2 -> A
    GITER(2, 1, 3, aA, bA, aB, bB)
    GITER(3, 2, 0, aB, bB, aA, bA)
  }
#undef GITER

  uint16_t* Dp = D;
  if constexpr (MODE == 3) Dp = D + (size_t)ks * PSTRIDE;
  // epilogue: C/D layout col=lane&15, row=(lane>>4)*4+reg; D row-major bf16
#pragma unroll
  for (int rt = 0; rt < AR; ++rt) {
#pragma unroll
    for (int r = 0; r < 4; ++r) {
      int rowg = (yF + wr * AR + rt) * 16 + (lane >> 4) * 4 + r;
      int b = rowg / CPB, c = rowg - b * CPB;
      int jj;
      if (MODE == 1) jj = (c < 2) ? (2 * s + c) : (4 + 16 * s + (c - 2));
      else jj = 16 * s + c;
      uint16_t* drow = Dp + (size_t)(b * OUTC + jj) * NNODE;
#pragma unroll
      for (int ct = 0; ct < BR; ++ct) {
        int colg = xF * 16 + (wc * BR + ct) * 16 + (lane & 15);
        drow[colg] = f2b(acc[rt][ct][r]);
      }
    }
  }
}

// ---------- stage2: r,u gates; X2 = r*prev -> fragment layout via LDS transpose ----------
__global__ __launch_bounds__(256) void stage2(
    const uint16_t* __restrict__ P1, const float* __restrict__ state,
    const float* __restrict__ rk, const float* __restrict__ uk,
    uint16_t* __restrict__ X2f, float* __restrict__ U) {
  __shared__ float s_rk[576], s_uk[576];
  __shared__ uint16_t s_x2[16 * 264];  // [k][i], padded stride (264) vs 256
  for (int i = threadIdx.x; i < 576; i += 256) { s_rk[i] = rk[i]; s_uk[i] = uk[i]; }
  __syncthreads();
  const int b = blockIdx.x >> 4, nb = blockIdx.x & 15;
  const int i = threadIdx.x;
  const int n = nb * 256 + i;
  float hs[36];
  const uint16_t* p = P1 + (size_t)b * 36 * NNODE + n;
#pragma unroll
  for (int j = 0; j < 36; ++j)
    hs[j] = b2f(p[(size_t)j * NNODE]);   // gemm1 full-K sums
  float ar[16], au[16];
#pragma unroll
  for (int k = 0; k < 16; ++k) { ar[k] = 0.f; au[k] = 0.f; }
#pragma unroll
  for (int j = 0; j < 36; ++j) {
    float h = hs[j];
#pragma unroll
    for (int k = 0; k < 16; ++k) {
      ar[k] += h * s_rk[j * 16 + k];
      au[k] += h * s_uk[j * 16 + k];
    }
  }
  const float* sp = state + (size_t)b * 65536 + n;
#pragma unroll
  for (int k = 0; k < 16; ++k) {
    float r = 1.f / (1.f + __expf(-ar[k]));
    float uu = 1.f / (1.f + __expf(-au[k]));
    float prev = sp[(size_t)k * NNODE];
    s_x2[k * 264 + i] = f2b(r * prev);
    U[(size_t)(b * 16 + k) * NNODE + n] = uu;
  }
  __syncthreads();
  // flush 4096 bf16 (16 k x 256 n) to fragment layout: contiguous 8KB region.
  uint16_t* region = X2f + ((size_t)b * 128 + nb * 8) * 512;
#pragma unroll
  for (int rr = 0; rr < 2; ++rr) {
    int fid = rr * 256 + i;
    int kk = fid & 15, qq = (fid >> 4) & 3, tl = fid >> 6;
    uint4 v = *(const uint4*)&s_x2[kk * 264 + tl * 32 + qq * 8];
    *(uint4*)(region + (size_t)fid * 8) = v;
  }
}

// ---------- stage4: c = tanh([h;D3]*ck); z = u*prev + (1-u)*c ----------
// OUTPUT LAYOUT: z is (B, N, U) reshaped -> out[b*65536 + n*16 + k]
__global__ __launch_bounds__(256) void stage4(
    const uint16_t* __restrict__ P1, const uint16_t* __restrict__ P3,
    const float* __restrict__ U, const float* __restrict__ state,
    const float* __restrict__ ck, float* __restrict__ out) {
  constexpr size_t PS3 = (size_t)64 * 32 * NNODE;
  __shared__ float s_ck[576];
  for (int i = threadIdx.x; i < 576; i += 256) s_ck[i] = ck[i];
  __syncthreads();
  int idx = blockIdx.x * 256 + threadIdx.x;
  int b = idx >> 12, n = idx & 4095;
  float hv[36];
  const uint16_t* p1 = P1 + (size_t)b * 36 * NNODE + n;
#pragma unroll
  for (int j = 0; j < 4; ++j)
    hv[j] = b2f(p1[(size_t)j * NNODE]);           // full-K gemm1
  const uint16_t* p3 = P3 + (size_t)b * 32 * NNODE + n;
#pragma unroll
  for (int j = 0; j < 32; ++j)                    // gemm2 KS2 partial sum
    hv[4 + j] = b2f(p3[(size_t)j * NNODE]) + b2f(p3[PS3 + (size_t)j * NNODE]);
  float ac[16];
#pragma unroll
  for (int k = 0; k < 16; ++k) ac[k] = 0.f;
#pragma unroll
  for (int j = 0; j < 36; ++j) {
    float h = hv[j];
#pragma unroll
    for (int k = 0; k < 16; ++k) ac[k] += h * s_ck[j * 16 + k];
  }
  const float* sp = state + (size_t)b * 65536 + n;
  const float* up = U + (size_t)b * 16 * NNODE + n;
  float z[16];
#pragma unroll
  for (int k = 0; k < 16; ++k) {
    float e = __expf(2.f * ac[k]);
    float c = 1.f - 2.f / (e + 1.f);  // tanh, saturates at +/-inf
    float uu = up[(size_t)k * NNODE];
    float prev = sp[(size_t)k * NNODE];
    z[k] = uu * prev + (1.f - uu) * c;
  }
  float4* po = (float4*)(out + (size_t)b * 65536 + (size_t)n * 16);
#pragma unroll
  for (int k4 = 0; k4 < 4; ++k4)
    po[k4] = make_float4(z[k4 * 4], z[k4 * 4 + 1], z[k4 * 4 + 2], z[k4 * 4 + 3]);
}

extern "C" void kernel_launch(void* const* d_in, const int* in_sizes, int n_in,
                              void* d_out, int out_size, void* d_ws, size_t ws_size,
                              hipStream_t stream) {
  const float* inputs = (const float*)d_in[0];
  const float* state = (const float*)d_in[1];
  const float* s0 = (const float*)d_in[2];
  const float* s1 = (const float*)d_in[3];
  const float* rk = (const float*)d_in[4];
  const float* uk = (const float*)d_in[5];
  const float* ck = (const float*)d_in[6];
  float* out = (float*)d_out;
  char* ws = (char*)d_ws;

  // workspace layout (bytes); X2f aliases X1f (dead after gemm1)
  uint16_t* S0f = (uint16_t*)(ws);                  // 33,554,432
  uint16_t* S1f = (uint16_t*)(ws + 33554432);       // 33,554,432
  uint16_t* X1f = (uint16_t*)(ws + 67108864);       // 9,437,184   (1152 x 4096 bf16, frag)
  uint16_t* X2f = (uint16_t*)(ws + 67108864);       // 8,388,608   (aliases X1f, frag)
  uint16_t* P1 = (uint16_t*)(ws + 76546048);        // 18,874,368  (full-K sums)
  float* U = (float*)(ws + 114294784);              // 16,777,216
  uint16_t* P3 = (uint16_t*)(ws + 131072000);       // 2 x 16,777,216 (KS2 partials)
  // total 164,626,432 bytes

  pack_all<<<dim3(256, 32, 3), 256, 0, stream>>>(inputs, state, s0, s1,
                                                 X1f, S0f, S1f);
  gemm_frag<1><<<dim3(16, 8, 2), 512, 0, stream>>>(X1f, S0f, S1f, P1);
  stage2<<<1024, 256, 0, stream>>>(P1, state, rk, uk, X2f, U);
  gemm_frag<3><<<dim3(16, 4, 4), 512, 0, stream>>>(X2f, S0f, S1f, P3);
  stage4<<<1024, 256, 0, stream>>>(P1, P3, U, state, ck, out);
}